// Round 4
// baseline (303.474 us; speedup 1.0000x reference)
//
#include <hip/hip_runtime.h>
#include <hip/hip_bf16.h>
#include <cstdint>

// GQA forward: B=2, N=2048, D_IN=2048, H=32, KV=8, G=4, DH=64
// bf16 MFMA pipeline: prep(cast+transposes) -> QKV GEMM -> V pre-transpose -> flash attn -> out GEMM
// Round 3: same as round 2 (256^2 pipelined GEMM, BK=32, 4-buf LDS ring, counted
// vmcnt, T2 swizzle, T5 setprio, T1 XCD swizzle) + compiler fences after raw barriers.

#define B_    2
#define N_    2048
#define DIN_  2048
#define H_    32
#define KV_   8
#define DH_   64
#define M_    4096      // B*N
#define NQKV_ 3072      // H*DH + 2*KV*DH

typedef float f32x4 __attribute__((ext_vector_type(4)));
typedef __bf16 bf16x8 __attribute__((ext_vector_type(8)));
typedef unsigned short u16x8 __attribute__((ext_vector_type(8)));

__device__ __forceinline__ unsigned short f32_to_bf16_bits(float f) {
  unsigned int u = __float_as_uint(f);
  u = (u + 0x7FFFu + ((u >> 16) & 1u)) >> 16;   // RNE
  return (unsigned short)u;
}

__device__ __forceinline__ void gload_lds16(const void* g, void* l) {
  __builtin_amdgcn_global_load_lds(
      (__attribute__((address_space(1))) void*)(g),
      (__attribute__((address_space(3))) void*)(l), 16, 0, 0);
}

// ---------------- fused prep: cast x -> bf16 (task 0), transpose-cast W (tasks 1-4) ----------------
__global__ __launch_bounds__(256) void prep(
    const float* __restrict__ x, const float* __restrict__ Wq,
    const float* __restrict__ Wk, const float* __restrict__ Wv,
    const float* __restrict__ Wo,
    unsigned short* __restrict__ Xb, unsigned short* __restrict__ Wqkv,
    unsigned short* __restrict__ Wot, float qscale) {
  const int task = blockIdx.y, tid = threadIdx.x;
  if (task == 0) {
    size_t i0 = ((size_t)blockIdx.x * 256 + tid) * 2;   // float4 index
#pragma unroll
    for (int t = 0; t < 2; ++t) {
      float4 v = ((const float4*)x)[i0 + t];
      ushort4 o;
      o.x = f32_to_bf16_bits(v.x);
      o.y = f32_to_bf16_bits(v.y);
      o.z = f32_to_bf16_bits(v.z);
      o.w = f32_to_bf16_bits(v.w);
      ((ushort4*)Xb)[i0 + t] = o;
    }
    return;
  }
  const float* src;
  unsigned short* dst;
  int NC, off;
  float scale = 1.0f;
  switch (task) {
    case 1: src = Wq; dst = Wqkv; NC = 2048; off = 0;    scale = qscale; break;
    case 2: src = Wk; dst = Wqkv; NC = 512;  off = 2048; break;
    case 3: src = Wv; dst = Wqkv; NC = 512;  off = 2560; break;
    default: src = Wo; dst = Wot; NC = 2048; off = 0;    break;
  }
  const int nx = NC >> 5;
  const int bx = blockIdx.x;
  if (bx >= nx * 64) return;
  const int n0 = (bx % nx) * 32, k0 = (bx / nx) * 32;
  __shared__ float tile[32][33];
  const int tx = tid & 31, ty = tid >> 5;
#pragma unroll
  for (int i = 0; i < 32; i += 8)
    tile[ty + i][tx] = src[(size_t)(k0 + ty + i) * NC + n0 + tx];
  __syncthreads();
#pragma unroll
  for (int i = 0; i < 32; i += 8)
    dst[(size_t)(off + n0 + ty + i) * 2048 + k0 + tx] =
        f32_to_bf16_bits(tile[tx][ty + i] * scale);
}

// ---------- pre-transpose V: QKV[:,2560+kv*64+d] -> Vtg[(bkv*64+d)*2048 + n] ----------
__global__ __launch_bounds__(256) void transpose_v(
    const unsigned short* __restrict__ QKV, unsigned short* __restrict__ Vtg) {
  __shared__ unsigned short t[64][72];
  int nt = blockIdx.x, bkv = blockIdx.y;
  int b = bkv >> 3, kv = bkv & 7;
  int tid = threadIdx.x;
  int row = tid >> 2, c = (tid & 3) * 16;
  const unsigned short* src =
      QKV + (size_t)(b * N_ + nt * 64 + row) * NQKV_ + 2560 + kv * 64;
  *(u16x8*)&t[row][c]     = *(const u16x8*)(src + c);
  *(u16x8*)&t[row][c + 8] = *(const u16x8*)(src + c + 8);
  __syncthreads();
  int d = tid >> 2;
  unsigned short* dst = Vtg + ((size_t)bkv * 64 + d) * N_ + nt * 64 + c;
  u16x8 o0, o1;
#pragma unroll
  for (int i = 0; i < 8; ++i) { o0[i] = t[c + i][d]; o1[i] = t[c + 8 + i][d]; }
  *(u16x8*)dst = o0;
  *(u16x8*)(dst + 8) = o1;
}

// ---------------- bf16 GEMM 256x256 tile, 8-phase-style pipelined schedule ----------------
// C(M,Nn) = A(M,K) @ Bt(Nn,K)^T. 512 threads = 8 waves (2M x 4N), per-wave 128x64.
// BK=32; LDS ring of 4 K-tiles (A 16KB + B 16KB each) = 128 KB.
// Per K-tile: 2 phases x {ds_read subtile, stage 1 half-tile (2 gload_lds),
// barrier, lgkmcnt(0), setprio(1), 16 MFMA, setprio(0), barrier}.
// Counted vmcnt(8) at tile top (2 tiles in flight); stage target = buffer freed
// 2 tiles ago -> WAR-safe: every wave drains lgkmcnt(0) on that buffer's last
// reads before the iter-top barrier that precedes the stage.
// T2 swizzle: LDS content at (row, slot) holds global k-chunk slot^((row>>1)&3);
// applied on gload source AND ds_read (rule #21); LDS dest stays lane-linear
// (m104/m108 constraint).
template <bool OUT_BF16, bool BIAS>
__global__ __launch_bounds__(512, 2) void gemm256(
    const unsigned short* __restrict__ A,
    const unsigned short* __restrict__ Bt,
    void* __restrict__ Cv,
    const float* __restrict__ bias,
    int Nn, int K, int nbx) {
  __shared__ unsigned short lds[4][2][8192];   // [buf][0=A,1=B][16KB region]

  const int tid = threadIdx.x;
  const int lane = tid & 63;
  const int wave = tid >> 6;
  const int wm = wave >> 2, wn = wave & 3;     // 2 x 4 wave grid
  const int l16 = lane & 15, quad = lane >> 4;

  // T1: XCD-aware bijective swizzle (nwg % 8 == 0 for all our grids)
  const int nwg = gridDim.x;
  const int orig = blockIdx.x;
  const int bid = (orig & 7) * (nwg >> 3) + (orig >> 3);
  const int m0 = (bid / nbx) * 256, n0 = (bid % nbx) * 256;

  const int T = K >> 5;                        // K-tiles of 32

  auto stage = [&](int t, int part, const unsigned short* src, int r0) {
    unsigned short* db = &lds[t & 3][part][0];
#pragma unroll
    for (int c = 0; c < 2; ++c) {
      int off = c * 8192 + tid * 16;           // byte offset in region (lane-linear)
      int row = off >> 6;                      // 0..255
      int kch = ((off >> 4) & 3) ^ ((row >> 1) & 3);   // inverse swizzle on source
      gload_lds16(src + (size_t)(r0 + row) * K + t * 32 + kch * 8,
                  (char*)db + off);
    }
  };

  f32x4 acc[8][4] = {};

  // prologue: stage tiles 0..2 into ring slots 0..2
#pragma unroll
  for (int t = 0; t < 3; ++t) {
    stage(t, 0, A, m0);
    stage(t, 1, Bt, n0);
  }

  for (int t = 0; t < T; ++t) {
    // gate: tile t landed (2 newer tiles may stay in flight = 8 loads/thread)
    if (t + 2 < T)      asm volatile("s_waitcnt vmcnt(8)" ::: "memory");
    else if (t + 1 < T) asm volatile("s_waitcnt vmcnt(4)" ::: "memory");
    else                asm volatile("s_waitcnt vmcnt(0)" ::: "memory");
    __builtin_amdgcn_s_barrier();
    asm volatile("" ::: "memory");             // pin loads below the barrier

    const char* Ab = (const char*)&lds[t & 3][0][0];
    const char* Bb = (const char*)&lds[t & 3][1][0];

    // ---- phase 0: A rows [wm*128, +64) + all B; stage A(t+3) ----
    bf16x8 a[4], b[4];
#pragma unroll
    for (int mi = 0; mi < 4; ++mi) {
      int row = wm * 128 + mi * 16 + l16;
      a[mi] = *(const bf16x8*)(Ab + row * 64 + (quad ^ ((row >> 1) & 3)) * 16);
    }
#pragma unroll
    for (int ni = 0; ni < 4; ++ni) {
      int row = wn * 64 + ni * 16 + l16;
      b[ni] = *(const bf16x8*)(Bb + row * 64 + (quad ^ ((row >> 1) & 3)) * 16);
    }
    if (t + 3 < T) stage(t + 3, 0, A, m0);
    asm volatile("" ::: "memory");
    __builtin_amdgcn_s_barrier();
    asm volatile("s_waitcnt lgkmcnt(0)" ::: "memory");
    __builtin_amdgcn_s_setprio(1);
#pragma unroll
    for (int mi = 0; mi < 4; ++mi)
#pragma unroll
      for (int ni = 0; ni < 4; ++ni)
        acc[mi][ni] = __builtin_amdgcn_mfma_f32_16x16x32_bf16(
            a[mi], b[ni], acc[mi][ni], 0, 0, 0);
    __builtin_amdgcn_s_setprio(0);
    asm volatile("" ::: "memory");
    __builtin_amdgcn_s_barrier();
    asm volatile("" ::: "memory");

    // ---- phase 1: A rows [wm*128+64, +64); stage B(t+3) ----
    bf16x8 a2[4];
#pragma unroll
    for (int mi = 0; mi < 4; ++mi) {
      int row = wm * 128 + 64 + mi * 16 + l16;
      a2[mi] = *(const bf16x8*)(Ab + row * 64 + (quad ^ ((row >> 1) & 3)) * 16);
    }
    if (t + 3 < T) stage(t + 3, 1, Bt, n0);
    asm volatile("" ::: "memory");
    __builtin_amdgcn_s_barrier();
    asm volatile("s_waitcnt lgkmcnt(0)" ::: "memory");
    __builtin_amdgcn_s_setprio(1);
#pragma unroll
    for (int mi = 0; mi < 4; ++mi)
#pragma unroll
      for (int ni = 0; ni < 4; ++ni)
        acc[mi + 4][ni] = __builtin_amdgcn_mfma_f32_16x16x32_bf16(
            a2[mi], b[ni], acc[mi + 4][ni], 0, 0, 0);
    __builtin_amdgcn_s_setprio(0);
    // no trailing barrier: next tile's vmcnt+barrier separates reads from stages
  }

  // epilogue
  unsigned short* Cb = (unsigned short*)Cv;
  float* Cf = (float*)Cv;
#pragma unroll
  for (int mi = 0; mi < 8; ++mi) {
    int rrow = m0 + wm * 128 + mi * 16 + quad * 4;
#pragma unroll
    for (int ni = 0; ni < 4; ++ni) {
      int col = n0 + wn * 64 + ni * 16 + l16;
      float bv = BIAS ? bias[col] : 0.0f;
#pragma unroll
      for (int r = 0; r < 4; ++r) {
        float v = acc[mi][ni][r] + bv;
        if (OUT_BF16)
          Cb[(size_t)(rrow + r) * Nn + col] = f32_to_bf16_bits(v);
        else
          Cf[(size_t)(rrow + r) * Nn + col] = v;
      }
    }
  }
}

// ---------------- flash attention (causal) ----------------
// Block = (qtile-pair p, kv*2+hp, b): 512 blocks, 2/CU. 2 heads share staged
// K/V (LDS dbuf via global_load_lds); wave = head (kv*4+hp*2+(w>>1)) x 32 rows
// ((w&1)*32), 2 strips of 16. qtile pair (31-p, p) -> exactly 33 K-iters.
// Ps double-buffered by iter parity. LDS = 64 KB exactly.
// Q pre-scaled by (1/8)*log2(e) in Wq; softmax = raw exp2, no max subtraction.
// T5: s_setprio(1) around MFMA clusters.
__global__ __launch_bounds__(256, 2) void attn_fwd(
    const unsigned short* __restrict__ QKV,   // (4096, 3072) bf16 [Q|K|V]
    const unsigned short* __restrict__ Vtg,   // (16*64, 2048) bf16 V^T per (b,kv)
    unsigned short* __restrict__ Ctx) {       // (4096, 2048) bf16
  __shared__ unsigned short Ks[2][64 * 64];        // 16 KB
  __shared__ unsigned short Vs[2][64 * 64];        // 16 KB
  __shared__ unsigned short Ps[2][4][2][16 * 64];  // 32 KB [parity][wave][strip]

  const int p = blockIdx.x;                      // 0..15
  const int kv = blockIdx.y >> 1, hp = blockIdx.y & 1;
  const int b = blockIdx.z;
  const int tid = threadIdx.x, lane = tid & 63, wave = tid >> 6;
  const int l16 = lane & 15, quad = lane >> 4;
  const int h = kv * 4 + hp * 2 + (wave >> 1);
  const int rhalf = (wave & 1) * 32;
  const size_t baserow = (size_t)b * N_;
  const unsigned short* Kg = QKV + 2048 + kv * 64;
  const unsigned short* Vg = Vtg + (size_t)(b * KV_ + kv) * 64 * N_;
  const unsigned short* Qbase = QKV + baserow * NQKV_ + h * 64;
  const int sw = l16 & 7;

  auto stageKV = [&](int j, int buf) {
#pragma unroll
    for (int it = 0; it < 2; ++it) {
      int c = tid + it * 256;
      int row = c >> 3, off = ((c & 7) ^ (row & 7)) * 8;
      gload_lds16(Kg + (baserow + j * 64 + row) * NQKV_ + off,
                  (char*)Ks[buf] + c * 16);
      gload_lds16(Vg + (size_t)row * N_ + j * 64 + off,
                  (char*)Vs[buf] + c * 16);
    }
  };

#pragma unroll 1
  for (int phase = 0; phase < 2; ++phase) {
    const int qtile = phase ? p : 31 - p;
    const int q0 = qtile * 64;

    // Q fragments direct from global (A-layout: row=l16, k=quad*8+j)
    bf16x8 qa[2][2];
#pragma unroll
    for (int s = 0; s < 2; ++s)
#pragma unroll
      for (int ks = 0; ks < 2; ++ks)
        qa[s][ks] = *(const bf16x8*)(Qbase +
            (size_t)(q0 + rhalf + s * 16 + l16) * NQKV_ + ks * 32 + quad * 8);

    f32x4 oacc[2][4] = {};
    float lp[2][4] = {};

    __syncthreads();            // previous phase's K/V readers done
    stageKV(0, 0);

    for (int j = 0; j <= qtile; ++j) {
      __syncthreads();          // staged buf visible (drains vmcnt)
      const int buf = j & 1;
      if (j < qtile) stageKV(j + 1, buf ^ 1);

      // K fragments (shared by both strips)
      bf16x8 kb[2][4];
#pragma unroll
      for (int ks = 0; ks < 2; ++ks)
#pragma unroll
        for (int ni = 0; ni < 4; ++ni)
          kb[ks][ni] = *(const bf16x8*)&Ks[buf][(ni * 16 + l16) * 64 +
                                               ((ks * 4 + quad) ^ sw) * 8];

      // per strip: S = Q K^T -> mask -> exp2 -> pack to Ps[parity]
#pragma unroll
      for (int s = 0; s < 2; ++s) {
        f32x4 sc[4] = {};
        __builtin_amdgcn_s_setprio(1);
#pragma unroll
        for (int ks = 0; ks < 2; ++ks)
#pragma unroll
          for (int ni = 0; ni < 4; ++ni)
            sc[ni] = __builtin_amdgcn_mfma_f32_16x16x32_bf16(
                qa[s][ks], kb[ks][ni], sc[ni], 0, 0, 0);
        __builtin_amdgcn_s_setprio(0);
        if (j == qtile) {   // causal mask, diagonal tile only
          const int qrow = q0 + rhalf + s * 16 + quad * 4;
#pragma unroll
          for (int ni = 0; ni < 4; ++ni) {
            int kcol = q0 + ni * 16 + l16;
#pragma unroll
            for (int r = 0; r < 4; ++r)
              if (kcol > qrow + r) sc[ni][r] = -1e30f;
          }
        }
        unsigned short* Pw = &Ps[buf][wave][s][0];
#pragma unroll
        for (int ni = 0; ni < 4; ++ni) {
          const int cl = ni * 2 + (l16 >> 3);
#pragma unroll
          for (int r = 0; r < 4; ++r) {
            float pe = __builtin_amdgcn_exp2f(sc[ni][r]);
            lp[s][r] += pe;
            int row = quad * 4 + r;
            Pw[row * 64 + ((cl ^ (row & 7)) * 8) + (l16 & 7)] =
                (unsigned short)(__float_as_uint(pe) >> 16);
          }
        }
      }

      // V fragments + P read back in A-layout; PV MFMA
      bf16x8 vb[2][4];
#pragma unroll
      for (int ks = 0; ks < 2; ++ks)
#pragma unroll
        for (int di = 0; di < 4; ++di)
          vb[ks][di] = *(const bf16x8*)&Vs[buf][(di * 16 + l16) * 64 +
                                               ((ks * 4 + quad) ^ sw) * 8];
#pragma unroll
      for (int s = 0; s < 2; ++s) {
        bf16x8 pa[2];
#pragma unroll
        for (int ks = 0; ks < 2; ++ks)
          pa[ks] = *(const bf16x8*)&Ps[buf][wave][s][l16 * 64 +
                                                    ((ks * 4 + quad) ^ sw) * 8];
        __builtin_amdgcn_s_setprio(1);
#pragma unroll
        for (int ks = 0; ks < 2; ++ks)
#pragma unroll
          for (int di = 0; di < 4; ++di)
            oacc[s][di] = __builtin_amdgcn_mfma_f32_16x16x32_bf16(
                pa[ks], vb[ks][di], oacc[s][di], 0, 0, 0);
        __builtin_amdgcn_s_setprio(0);
      }
    }

    // normalize + write
#pragma unroll
    for (int s = 0; s < 2; ++s) {
      float inv[4];
#pragma unroll
      for (int r = 0; r < 4; ++r) {
        float v = lp[s][r];
#pragma unroll
        for (int off = 1; off < 16; off <<= 1) v += __shfl_xor(v, off);
        inv[r] = 1.0f / v;
      }
#pragma unroll
      for (int di = 0; di < 4; ++di)
#pragma unroll
        for (int r = 0; r < 4; ++r) {
          size_t row = baserow + q0 + rhalf + s * 16 + quad * 4 + r;
          Ctx[row * 2048 + h * 64 + di * 16 + l16] =
              f32_to_bf16_bits(oacc[s][di][r] * inv[r]);
        }
    }
  }
}

extern "C" void kernel_launch(void* const* d_in, const int* in_sizes, int n_in,
                              void* d_out, int out_size, void* d_ws, size_t ws_size,
                              hipStream_t stream) {
  const float* x  = (const float*)d_in[0];
  const float* Wq = (const float*)d_in[1];
  const float* Wk = (const float*)d_in[2];
  const float* Wv = (const float*)d_in[3];
  const float* Wo = (const float*)d_in[4];
  const float* bo = (const float*)d_in[5];
  float* out = (float*)d_out;

  // workspace layout (bf16 = ushort): 60 MB total
  unsigned short* Xb   = (unsigned short*)d_ws;              // 4096x2048 (16 MB)
  unsigned short* Wqkv = Xb + (size_t)M_ * DIN_;             // 3072x2048 (12 MB)
  unsigned short* QKV  = Wqkv + (size_t)NQKV_ * DIN_;        // 4096x3072 (24 MB)
  unsigned short* Wot  = QKV + (size_t)M_ * NQKV_;           // 2048x2048 (8 MB)
  unsigned short* Ctx  = Xb;    // alias: Xb dead after QKV GEMM
  unsigned short* Vtg  = Wqkv;  // alias: Wqkv dead after QKV GEMM (4 MB)

  const float kQScale = 0.125f * 1.44269504088896340736f;  // (1/sqrt(DH)) * log2(e)

  prep<<<dim3(4096, 5), 256, 0, stream>>>(x, Wq, Wk, Wv, Wo, Xb, Wqkv, Wot, kQScale);

  // QKV GEMM: (4096x2048) @ (3072x2048)^T -> 16 x 12 = 192 blocks
  gemm256<true, false><<<dim3(192), 512, 0, stream>>>(
      Xb, Wqkv, QKV, nullptr, NQKV_, DIN_, NQKV_ / 256);

  transpose_v<<<dim3(N_ / 64, B_ * KV_), 256, 0, stream>>>(QKV, Vtg);

  attn_fwd<<<dim3(16, 16, 2), 256, 0, stream>>>(QKV, Vtg, Ctx);

  // out GEMM: (4096x2048) @ (2048x2048)^T -> 16 x 8 = 128 blocks
  gemm256<false, true><<<dim3(128), 512, 0, stream>>>(
      Ctx, Wot, out, bo, DIN_, 2048, DIN_ / 256);
}

// Round 5
// 288.049 us; speedup vs baseline: 1.0535x; 1.0535x over previous
//
#include <hip/hip_runtime.h>
#include <hip/hip_bf16.h>
#include <cstdint>

// GQA forward: B=2, N=2048, D_IN=2048, H=32, KV=8, G=4, DH=64
// Round 5: GEMM rebuilt as 128^2 tile, 4-wave, 2 blocks/CU, register-fragment
// software pipeline: ds_reads(t+1) issued before MFMA(t), no waitcnt between
// (compiler emits counted lgkmcnt); 1 barrier/K-tile; stage AFTER barrier so
// slot WAR is proven by barrier order; counted vmcnt(4) steady-state.

#define B_    2
#define N_    2048
#define DIN_  2048
#define H_    32
#define KV_   8
#define DH_   64
#define M_    4096      // B*N
#define NQKV_ 3072      // H*DH + 2*KV*DH

typedef float f32x4 __attribute__((ext_vector_type(4)));
typedef __bf16 bf16x8 __attribute__((ext_vector_type(8)));
typedef unsigned short u16x8 __attribute__((ext_vector_type(8)));

__device__ __forceinline__ unsigned short f32_to_bf16_bits(float f) {
  unsigned int u = __float_as_uint(f);
  u = (u + 0x7FFFu + ((u >> 16) & 1u)) >> 16;   // RNE
  return (unsigned short)u;
}

__device__ __forceinline__ void gload_lds16(const void* g, void* l) {
  __builtin_amdgcn_global_load_lds(
      (__attribute__((address_space(1))) void*)(g),
      (__attribute__((address_space(3))) void*)(l), 16, 0, 0);
}

// ---------------- fused prep: cast x -> bf16 (task 0), transpose-cast W (tasks 1-4) ----------------
__global__ __launch_bounds__(256) void prep(
    const float* __restrict__ x, const float* __restrict__ Wq,
    const float* __restrict__ Wk, const float* __restrict__ Wv,
    const float* __restrict__ Wo,
    unsigned short* __restrict__ Xb, unsigned short* __restrict__ Wqkv,
    unsigned short* __restrict__ Wot, float qscale) {
  const int task = blockIdx.y, tid = threadIdx.x;
  if (task == 0) {
    size_t i0 = ((size_t)blockIdx.x * 256 + tid) * 2;   // float4 index
#pragma unroll
    for (int t = 0; t < 2; ++t) {
      float4 v = ((const float4*)x)[i0 + t];
      ushort4 o;
      o.x = f32_to_bf16_bits(v.x);
      o.y = f32_to_bf16_bits(v.y);
      o.z = f32_to_bf16_bits(v.z);
      o.w = f32_to_bf16_bits(v.w);
      ((ushort4*)Xb)[i0 + t] = o;
    }
    return;
  }
  const float* src;
  unsigned short* dst;
  int NC, off;
  float scale = 1.0f;
  switch (task) {
    case 1: src = Wq; dst = Wqkv; NC = 2048; off = 0;    scale = qscale; break;
    case 2: src = Wk; dst = Wqkv; NC = 512;  off = 2048; break;
    case 3: src = Wv; dst = Wqkv; NC = 512;  off = 2560; break;
    default: src = Wo; dst = Wot; NC = 2048; off = 0;    break;
  }
  const int nx = NC >> 5;
  const int bx = blockIdx.x;
  if (bx >= nx * 64) return;
  const int n0 = (bx % nx) * 32, k0 = (bx / nx) * 32;
  __shared__ float tile[32][33];
  const int tx = tid & 31, ty = tid >> 5;
#pragma unroll
  for (int i = 0; i < 32; i += 8)
    tile[ty + i][tx] = src[(size_t)(k0 + ty + i) * NC + n0 + tx];
  __syncthreads();
#pragma unroll
  for (int i = 0; i < 32; i += 8)
    dst[(size_t)(off + n0 + ty + i) * 2048 + k0 + tx] =
        f32_to_bf16_bits(tile[tx][ty + i] * scale);
}

// ---------- pre-transpose V: QKV[:,2560+kv*64+d] -> Vtg[(bkv*64+d)*2048 + n] ----------
__global__ __launch_bounds__(256) void transpose_v(
    const unsigned short* __restrict__ QKV, unsigned short* __restrict__ Vtg) {
  __shared__ unsigned short t[64][72];
  int nt = blockIdx.x, bkv = blockIdx.y;
  int b = bkv >> 3, kv = bkv & 7;
  int tid = threadIdx.x;
  int row = tid >> 2, c = (tid & 3) * 16;
  const unsigned short* src =
      QKV + (size_t)(b * N_ + nt * 64 + row) * NQKV_ + 2560 + kv * 64;
  *(u16x8*)&t[row][c]     = *(const u16x8*)(src + c);
  *(u16x8*)&t[row][c + 8] = *(const u16x8*)(src + c + 8);
  __syncthreads();
  int d = tid >> 2;
  unsigned short* dst = Vtg + ((size_t)bkv * 64 + d) * N_ + nt * 64 + c;
  u16x8 o0, o1;
#pragma unroll
  for (int i = 0; i < 8; ++i) { o0[i] = t[c + i][d]; o1[i] = t[c + 8 + i][d]; }
  *(u16x8*)dst = o0;
  *(u16x8*)(dst + 8) = o1;
}

// ------------- bf16 GEMM 128x128 tile, register-fragment software pipeline -------------
// C(M,Nn) = A(M,K) @ Bt(Nn,K)^T. 256 threads = 4 waves (2x2), per-wave 64x64.
// BK=32; LDS ring of 4 slots x (A 8KB + B 8KB) = 64 KB -> 2 blocks/CU.
// Per K-tile t: { vmcnt(4) [tile t+1 landed], barrier, stage(t+3) [after barrier
// => slot WAR proven: all waves' frags(t-1) reads completed before their body
// t-1 MFMA, hence before this barrier], ds_read frags(t+1) -> F_nxt,
// sched_barrier, MFMA x16 on F_cur }. No waitcnt between reads and MFMA:
// compiler emits counted lgkmcnt(8) gating only NEXT body's MFMAs -> LDS pipe
// and matrix pipe overlap. Swizzle: LDS (row,slot16) holds global k-chunk
// slot^((row>>1)&3); read slot = quad^((l16>>1)&3) (lane-static). 0 conflicts
// (verified round 4).
template <bool OUT_BF16, bool BIAS>
__global__ __launch_bounds__(256, 2) void gemm128p(
    const unsigned short* __restrict__ A,
    const unsigned short* __restrict__ Bt,
    void* __restrict__ Cv,
    const float* __restrict__ bias,
    int Nn, int K, int nbx) {
  __shared__ unsigned short lds[4][2][4096];   // [slot][0=A,1=B][8KB]

  const int tid = threadIdx.x;
  const int lane = tid & 63;
  const int wave = tid >> 6;                   // 0..3
  const int wm = wave >> 1, wn = wave & 1;     // 2x2 wave grid, per-wave 64x64
  const int l16 = lane & 15, quad = lane >> 4;

  // T1: XCD-aware bijective swizzle (grids are multiples of 8)
  const int nwg = gridDim.x;
  const int orig = blockIdx.x;
  const int bid = (orig & 7) * (nwg >> 3) + (orig >> 3);
  const int m0 = (bid / nbx) * 128, n0 = (bid % nbx) * 128;

  const int T = K >> 5;                        // K-tiles of 32 (T=64, even)

  auto stage = [&](int t) {
    const int slot = t & 3;
#pragma unroll
    for (int c = 0; c < 2; ++c) {
      int off = c * 4096 + tid * 16;           // byte offset in 8KB region
      int row = off >> 6;                      // 0..127
      int kch = ((off >> 4) & 3) ^ ((row >> 1) & 3);   // inverse swizzle on src
      gload_lds16(A + (size_t)(m0 + row) * K + t * 32 + kch * 8,
                  (char*)&lds[slot][0][0] + off);
      gload_lds16(Bt + (size_t)(n0 + row) * K + t * 32 + kch * 8,
                  (char*)&lds[slot][1][0] + off);
    }
  };

  // lane-static read byte-offsets within a region (mi/ni add 1024 B)
  const int swz = (quad ^ ((l16 >> 1) & 3)) * 16;
  const int rdA = (wm * 64 + l16) * 64 + swz;
  const int rdB = (wn * 64 + l16) * 64 + swz;

  auto rdfrags = [&](int tt, bf16x8 (&fa)[4], bf16x8 (&fb)[4]) {
    const char* Ab = (const char*)&lds[tt & 3][0][0];
    const char* Bb = (const char*)&lds[tt & 3][1][0];
#pragma unroll
    for (int mi = 0; mi < 4; ++mi)
      fa[mi] = *(const bf16x8*)(Ab + rdA + mi * 1024);
#pragma unroll
    for (int ni = 0; ni < 4; ++ni)
      fb[ni] = *(const bf16x8*)(Bb + rdB + ni * 1024);
  };

  f32x4 acc[4][4] = {};

  auto domfma = [&](bf16x8 (&fa)[4], bf16x8 (&fb)[4]) {
    __builtin_amdgcn_s_setprio(1);
#pragma unroll
    for (int mi = 0; mi < 4; ++mi)
#pragma unroll
      for (int ni = 0; ni < 4; ++ni)
        acc[mi][ni] = __builtin_amdgcn_mfma_f32_16x16x32_bf16(
            fa[mi], fb[ni], acc[mi][ni], 0, 0, 0);
    __builtin_amdgcn_s_setprio(0);
  };

  // gate for body t: tile t+1 must be landed (for rdfrags), then barrier
  // (certifies all waves' frags(t-1) reads done), then stage(t+3).
  auto gate = [&](int t) {
    if (t + 2 < T)      asm volatile("s_waitcnt vmcnt(4)" ::: "memory");
    else if (t + 1 < T) asm volatile("s_waitcnt vmcnt(0)" ::: "memory");
    __builtin_amdgcn_s_barrier();
    asm volatile("" ::: "memory");             // pin memory ops below barrier
    if (t + 3 < T) stage(t + 3);
  };

  bf16x8 Aa[4], Ab_[4], Ba[4], Bb_[4];         // two named frag buffers

  // prologue: stage tiles 0..2; read frags(0)
  stage(0); stage(1); stage(2);
  asm volatile("s_waitcnt vmcnt(8)" ::: "memory");   // tile 0 landed
  __builtin_amdgcn_s_barrier();
  asm volatile("" ::: "memory");
  rdfrags(0, Aa, Ba);

  for (int t = 0; t < T; t += 2) {
    // even body: MFMA frags(t) in {Aa,Ba}; read frags(t+1) into {Ab_,Bb_}
    gate(t);
    rdfrags(t + 1, Ab_, Bb_);                  // t+1 < T always (t <= T-2)
    __builtin_amdgcn_sched_barrier(0);
    domfma(Aa, Ba);
    // odd body: MFMA frags(t+1); read frags(t+2) into {Aa,Ba}
    gate(t + 1);
    if (t + 2 < T) rdfrags(t + 2, Aa, Ba);
    __builtin_amdgcn_sched_barrier(0);
    domfma(Ab_, Bb_);
  }

  // epilogue
  unsigned short* Cb = (unsigned short*)Cv;
  float* Cf = (float*)Cv;
#pragma unroll
  for (int mi = 0; mi < 4; ++mi) {
    int rrow = m0 + wm * 64 + mi * 16 + quad * 4;
#pragma unroll
    for (int ni = 0; ni < 4; ++ni) {
      int col = n0 + wn * 64 + ni * 16 + l16;
      float bv = BIAS ? bias[col] : 0.0f;
#pragma unroll
      for (int r = 0; r < 4; ++r) {
        float v = acc[mi][ni][r] + bv;
        if (OUT_BF16)
          Cb[(size_t)(rrow + r) * Nn + col] = f32_to_bf16_bits(v);
        else
          Cf[(size_t)(rrow + r) * Nn + col] = v;
      }
    }
  }
}

// ---------------- flash attention (causal) ----------------
// Block = (qtile-pair p, kv*2+hp, b): 512 blocks, 2/CU. 2 heads share staged
// K/V (LDS dbuf via global_load_lds); wave = head x 32 rows, 2 strips of 16.
// qtile pair (31-p, p) -> exactly 33 K-iters. Ps double-buffered by parity.
// Q pre-scaled by (1/8)*log2(e) in Wq; softmax = raw exp2, no max subtraction.
// T5: s_setprio(1) around MFMA clusters.
__global__ __launch_bounds__(256, 2) void attn_fwd(
    const unsigned short* __restrict__ QKV,   // (4096, 3072) bf16 [Q|K|V]
    const unsigned short* __restrict__ Vtg,   // (16*64, 2048) bf16 V^T per (b,kv)
    unsigned short* __restrict__ Ctx) {       // (4096, 2048) bf16
  __shared__ unsigned short Ks[2][64 * 64];        // 16 KB
  __shared__ unsigned short Vs[2][64 * 64];        // 16 KB
  __shared__ unsigned short Ps[2][4][2][16 * 64];  // 32 KB [parity][wave][strip]

  const int p = blockIdx.x;                      // 0..15
  const int kv = blockIdx.y >> 1, hp = blockIdx.y & 1;
  const int b = blockIdx.z;
  const int tid = threadIdx.x, lane = tid & 63, wave = tid >> 6;
  const int l16 = lane & 15, quad = lane >> 4;
  const int h = kv * 4 + hp * 2 + (wave >> 1);
  const int rhalf = (wave & 1) * 32;
  const size_t baserow = (size_t)b * N_;
  const unsigned short* Kg = QKV + 2048 + kv * 64;
  const unsigned short* Vg = Vtg + (size_t)(b * KV_ + kv) * 64 * N_;
  const unsigned short* Qbase = QKV + baserow * NQKV_ + h * 64;
  const int sw = l16 & 7;

  auto stageKV = [&](int j, int buf) {
#pragma unroll
    for (int it = 0; it < 2; ++it) {
      int c = tid + it * 256;
      int row = c >> 3, off = ((c & 7) ^ (row & 7)) * 8;
      gload_lds16(Kg + (baserow + j * 64 + row) * NQKV_ + off,
                  (char*)Ks[buf] + c * 16);
      gload_lds16(Vg + (size_t)row * N_ + j * 64 + off,
                  (char*)Vs[buf] + c * 16);
    }
  };

#pragma unroll 1
  for (int phase = 0; phase < 2; ++phase) {
    const int qtile = phase ? p : 31 - p;
    const int q0 = qtile * 64;

    // Q fragments direct from global (A-layout: row=l16, k=quad*8+j)
    bf16x8 qa[2][2];
#pragma unroll
    for (int s = 0; s < 2; ++s)
#pragma unroll
      for (int ks = 0; ks < 2; ++ks)
        qa[s][ks] = *(const bf16x8*)(Qbase +
            (size_t)(q0 + rhalf + s * 16 + l16) * NQKV_ + ks * 32 + quad * 8);

    f32x4 oacc[2][4] = {};
    float lp[2][4] = {};

    __syncthreads();            // previous phase's K/V readers done
    stageKV(0, 0);

    for (int j = 0; j <= qtile; ++j) {
      __syncthreads();          // staged buf visible (drains vmcnt)
      const int buf = j & 1;
      if (j < qtile) stageKV(j + 1, buf ^ 1);

      // K fragments (shared by both strips)
      bf16x8 kb[2][4];
#pragma unroll
      for (int ks = 0; ks < 2; ++ks)
#pragma unroll
        for (int ni = 0; ni < 4; ++ni)
          kb[ks][ni] = *(const bf16x8*)&Ks[buf][(ni * 16 + l16) * 64 +
                                               ((ks * 4 + quad) ^ sw) * 8];

      // per strip: S = Q K^T -> mask -> exp2 -> pack to Ps[parity]
#pragma unroll
      for (int s = 0; s < 2; ++s) {
        f32x4 sc[4] = {};
        __builtin_amdgcn_s_setprio(1);
#pragma unroll
        for (int ks = 0; ks < 2; ++ks)
#pragma unroll
          for (int ni = 0; ni < 4; ++ni)
            sc[ni] = __builtin_amdgcn_mfma_f32_16x16x32_bf16(
                qa[s][ks], kb[ks][ni], sc[ni], 0, 0, 0);
        __builtin_amdgcn_s_setprio(0);
        if (j == qtile) {   // causal mask, diagonal tile only
          const int qrow = q0 + rhalf + s * 16 + quad * 4;
#pragma unroll
          for (int ni = 0; ni < 4; ++ni) {
            int kcol = q0 + ni * 16 + l16;
#pragma unroll
            for (int r = 0; r < 4; ++r)
              if (kcol > qrow + r) sc[ni][r] = -1e30f;
          }
        }
        unsigned short* Pw = &Ps[buf][wave][s][0];
#pragma unroll
        for (int ni = 0; ni < 4; ++ni) {
          const int cl = ni * 2 + (l16 >> 3);
#pragma unroll
          for (int r = 0; r < 4; ++r) {
            float pe = __builtin_amdgcn_exp2f(sc[ni][r]);
            lp[s][r] += pe;
            int row = quad * 4 + r;
            Pw[row * 64 + ((cl ^ (row & 7)) * 8) + (l16 & 7)] =
                (unsigned short)(__float_as_uint(pe) >> 16);
          }
        }
      }

      // V fragments + P read back in A-layout; PV MFMA
      bf16x8 vb[2][4];
#pragma unroll
      for (int ks = 0; ks < 2; ++ks)
#pragma unroll
        for (int di = 0; di < 4; ++di)
          vb[ks][di] = *(const bf16x8*)&Vs[buf][(di * 16 + l16) * 64 +
                                               ((ks * 4 + quad) ^ sw) * 8];
#pragma unroll
      for (int s = 0; s < 2; ++s) {
        bf16x8 pa[2];
#pragma unroll
        for (int ks = 0; ks < 2; ++ks)
          pa[ks] = *(const bf16x8*)&Ps[buf][wave][s][l16 * 64 +
                                                    ((ks * 4 + quad) ^ sw) * 8];
        __builtin_amdgcn_s_setprio(1);
#pragma unroll
        for (int ks = 0; ks < 2; ++ks)
#pragma unroll
          for (int di = 0; di < 4; ++di)
            oacc[s][di] = __builtin_amdgcn_mfma_f32_16x16x32_bf16(
                pa[ks], vb[ks][di], oacc[s][di], 0, 0, 0);
        __builtin_amdgcn_s_setprio(0);
      }
    }

    // normalize + write
#pragma unroll
    for (int s = 0; s < 2; ++s) {
      float inv[4];
#pragma unroll
      for (int r = 0; r < 4; ++r) {
        float v = lp[s][r];
#pragma unroll
        for (int off = 1; off < 16; off <<= 1) v += __shfl_xor(v, off);
        inv[r] = 1.0f / v;
      }
#pragma unroll
      for (int di = 0; di < 4; ++di)
#pragma unroll
        for (int r = 0; r < 4; ++r) {
          size_t row = baserow + q0 + rhalf + s * 16 + quad * 4 + r;
          Ctx[row * 2048 + h * 64 + di * 16 + l16] =
              f32_to_bf16_bits(oacc[s][di][r] * inv[r]);
        }
    }
  }
}

extern "C" void kernel_launch(void* const* d_in, const int* in_sizes, int n_in,
                              void* d_out, int out_size, void* d_ws, size_t ws_size,
                              hipStream_t stream) {
  const float* x  = (const float*)d_in[0];
  const float* Wq = (const float*)d_in[1];
  const float* Wk = (const float*)d_in[2];
  const float* Wv = (const float*)d_in[3];
  const float* Wo = (const float*)d_in[4];
  const float* bo = (const float*)d_in[5];
  float* out = (float*)d_out;

  // workspace layout (bf16 = ushort): 60 MB total
  unsigned short* Xb   = (unsigned short*)d_ws;              // 4096x2048 (16 MB)
  unsigned short* Wqkv = Xb + (size_t)M_ * DIN_;             // 3072x2048 (12 MB)
  unsigned short* QKV  = Wqkv + (size_t)NQKV_ * DIN_;        // 4096x3072 (24 MB)
  unsigned short* Wot  = QKV + (size_t)M_ * NQKV_;           // 2048x2048 (8 MB)
  unsigned short* Ctx  = Xb;    // alias: Xb dead after QKV GEMM
  unsigned short* Vtg  = Wqkv;  // alias: Wqkv dead after QKV GEMM (4 MB)

  const float kQScale = 0.125f * 1.44269504088896340736f;  // (1/sqrt(DH)) * log2(e)

  prep<<<dim3(4096, 5), 256, 0, stream>>>(x, Wq, Wk, Wv, Wo, Xb, Wqkv, Wot, kQScale);

  // QKV GEMM: (4096x2048) @ (3072x2048)^T -> 32 x 24 = 768 blocks (3 full waves)
  gemm128p<true, false><<<dim3(768), 256, 0, stream>>>(
      Xb, Wqkv, QKV, nullptr, NQKV_, DIN_, NQKV_ / 128);

  transpose_v<<<dim3(N_ / 64, B_ * KV_), 256, 0, stream>>>(QKV, Vtg);

  attn_fwd<<<dim3(16, 16, 2), 256, 0, stream>>>(QKV, Vtg, Ctx);

  // out GEMM: (4096x2048) @ (2048x2048)^T -> 32 x 16 = 512 blocks (2 full waves)
  gemm128p<false, true><<<dim3(512), 256, 0, stream>>>(
      Ctx, Wot, out, bo, DIN_, 2048, DIN_ / 128);
}